// Round 5
// baseline (323.344 us; speedup 1.0000x reference)
//
#include <hip/hip_runtime.h>
#include <hip/hip_bf16.h>

#define B_SZ 16384
#define SRCN 200
#define CAT  10
#define IN   2000
#define KPAD 2048
#define TBYTES 40960       // one table: 10 * 2048 * 2B
#define NBLK 1024
#define EPSF 1e-10f

typedef short short8 __attribute__((ext_vector_type(8)));

// round-to-nearest-even f32 -> bf16 (bit trick)
__device__ __forceinline__ short f2bf(float f) {
    union { float f; unsigned u; } v; v.f = f;
    unsigned r = (v.u + 0x7fffu + ((v.u >> 16) & 1u)) >> 16;
    return (short)r;
}

__device__ __forceinline__ void bf2x2(unsigned u, float& a, float& b) {
    union { unsigned u; float f; } lo, hi;
    lo.u = u << 16; hi.u = u & 0xffff0000u;
    a = lo.f; b = hi.f;
}

// ---------------------------------------------------------------------------
// Prep: bf16 tables logp_t[10][2048], wyc_t[10][2048] (zero-padded cols),
// l1 = sum|W_yc| -> acc[2].
// ---------------------------------------------------------------------------
__global__ void prep_kernel(const float* __restrict__ W_rec,
                            const float* __restrict__ b_rec,
                            const float* __restrict__ W_yc,
                            short* __restrict__ logp_t,
                            short* __restrict__ wyc_t,
                            double* __restrict__ acc) {
    if (blockIdx.x == gridDim.x - 1) {
        float p = 0.f;
        for (int i = threadIdx.x; i < IN * CAT; i += blockDim.x) p += fabsf(W_yc[i]);
        __shared__ float red[4];
        for (int o = 32; o; o >>= 1) p += __shfl_down(p, o, 64);
        if ((threadIdx.x & 63) == 0) red[threadIdx.x >> 6] = p;
        __syncthreads();
        if (threadIdx.x == 0) acc[2] = (double)(red[0] + red[1] + red[2] + red[3]);
        return;
    }
    int tid = blockIdx.x * blockDim.x + threadIdx.x;   // 0 .. 20479
    int n = tid >> 11;          // 0..9
    int k = tid & 2047;
    short wv = 0, lv = 0;
    if (k < IN) {
        wv = f2bf(W_yc[k * CAT + n]);
        int base = (k / CAT) * CAT;
        float lg[CAT];
        float m = -1e30f;
        #pragma unroll
        for (int i = 0; i < CAT; i++) {
            lg[i] = W_rec[n * IN + base + i] + b_rec[base + i];
            m = fmaxf(m, lg[i]);
        }
        float s = 0.f;
        #pragma unroll
        for (int i = 0; i < CAT; i++) s += expf(lg[i] - m);
        float myl = W_rec[n * IN + k] + b_rec[k];
        float pp = expf(myl - m) / s;
        lv = f2bf(logf(EPSF + pp));
    }
    wyc_t[n * KPAD + k] = wv;
    logp_t[n * KPAD + k] = lv;
}

// ---------------------------------------------------------------------------
// Main: pure streaming VALU. Block = 512 threads (8 waves), 80 KB LDS tables
// (exactly 2 blocks/CU -> 16 waves/CU). Wave owns 2 rows; lane l streams cols
// {l*4 + 256*i} as float4 (contiguous 1KB per wave-load, register
// double-buffered). 40 f32 accumulators/lane, butterfly-reduced at the end.
// No barriers in the main loop, no MFMA, no DMA.
// ---------------------------------------------------------------------------
__global__ __launch_bounds__(512, 4) void main_kernel(
        const float* __restrict__ x, const float* __restrict__ mask,
        const float* __restrict__ y_target, const float* __restrict__ b_yc,
        const short* __restrict__ logp_t, const short* __restrict__ wyc_t,
        float* __restrict__ out, float2* __restrict__ part) {
    __shared__ __attribute__((aligned(16))) char lds[2 * TBYTES];   // 80 KB

    const int tid = threadIdx.x;
    {   // stage both tables: 2*2560 short8
        short8* d = (short8*)lds;
        const short8* s1 = (const short8*)logp_t;
        const short8* s2 = (const short8*)wyc_t;
        #pragma unroll
        for (int i = 0; i < 5; ++i) {
            d[i * 512 + tid]        = s1[i * 512 + tid];
            d[2560 + i * 512 + tid] = s2[i * 512 + tid];
        }
    }
    __syncthreads();

    const int l  = tid & 63;
    const int w  = tid >> 6;                // 0..7
    const int r0 = (blockIdx.x * 8 + w) * 2;

    const float* xr0 = x + (size_t)r0 * IN;
    const float* xr1 = xr0 + IN;
    const float* mr0 = mask + (size_t)r0 * IN;
    const float* mr1 = mr0 + IN;

    float pR0[CAT], pR1[CAT], pW0[CAT], pW1[CAT];
    #pragma unroll
    for (int c = 0; c < CAT; ++c) { pR0[c] = pR1[c] = pW0[c] = pW1[c] = 0.f; }

    const int c0 = l * 4;
    float4 cx0 = *(const float4*)(xr0 + c0);
    float4 cx1 = *(const float4*)(xr1 + c0);
    float4 cm0 = *(const float4*)(mr0 + c0);
    float4 cm1 = *(const float4*)(mr1 + c0);

    #pragma unroll
    for (int i = 0; i < 8; ++i) {
        // prefetch next strip (register double-buffer)
        float4 nx0 = {0,0,0,0}, nx1 = {0,0,0,0}, nm0 = {0,0,0,0}, nm1 = {0,0,0,0};
        if (i < 7) {
            const int nb = (i + 1) * 256 + l * 4;
            if ((i < 6) || (nb + 3 < IN)) {     // i<6 folds to unconditional
                nx0 = *(const float4*)(xr0 + nb);
                nx1 = *(const float4*)(xr1 + nb);
                nm0 = *(const float4*)(mr0 + nb);
                nm1 = *(const float4*)(mr1 + nb);
            }
        }
        const float X0[4] = {cx0.x, cx0.y, cx0.z, cx0.w};
        const float X1[4] = {cx1.x, cx1.y, cx1.z, cx1.w};
        const float XM0[4] = {cx0.x * cm0.x, cx0.y * cm0.y, cx0.z * cm0.z, cx0.w * cm0.w};
        const float XM1[4] = {cx1.x * cm1.x, cx1.y * cm1.y, cx1.z * cm1.z, cx1.w * cm1.w};

        const int off = i * 512 + l * 8;        // byte offset within a table row
        #pragma unroll
        for (int c = 0; c < CAT; ++c) {
            const uint2 ulp = *(const uint2*)(lds + c * 4096 + off);
            const uint2 uwy = *(const uint2*)(lds + TBYTES + c * 4096 + off);
            float l0, l1v, l2, l3, w0, w1, w2, w3;
            bf2x2(ulp.x, l0, l1v); bf2x2(ulp.y, l2, l3);
            bf2x2(uwy.x, w0, w1);  bf2x2(uwy.y, w2, w3);
            pR0[c] += XM0[0] * l0 + XM0[1] * l1v + XM0[2] * l2 + XM0[3] * l3;
            pR1[c] += XM1[0] * l0 + XM1[1] * l1v + XM1[2] * l2 + XM1[3] * l3;
            pW0[c] += X0[0] * w0 + X0[1] * w1 + X0[2] * w2 + X0[3] * w3;
            pW1[c] += X1[0] * w0 + X1[1] * w1 + X1[2] * w2 + X1[3] * w3;
        }
        cx0 = nx0; cx1 = nx1; cm0 = nm0; cm1 = nm1;
    }

    // ---- cross-lane reduce all 40 accumulators
    #pragma unroll
    for (int c = 0; c < CAT; ++c) {
        #pragma unroll
        for (int o = 1; o < 64; o <<= 1) {
            pR0[c] += __shfl_xor(pR0[c], o, 64);
            pR1[c] += __shfl_xor(pR1[c], o, 64);
            pW0[c] += __shfl_xor(pW0[c], o, 64);
            pW1[c] += __shfl_xor(pW1[c], o, 64);
        }
    }

    // ---- softmax + losses (computed redundantly on all lanes)
    float y0[CAT], y1[CAT];
    float mx0 = -1e30f, mx1 = -1e30f;
    #pragma unroll
    for (int c = 0; c < CAT; ++c) {
        const float by = b_yc[c];
        pW0[c] += by; pW1[c] += by;
        mx0 = fmaxf(mx0, pW0[c]); mx1 = fmaxf(mx1, pW1[c]);
    }
    float s0 = 0.f, s1 = 0.f;
    #pragma unroll
    for (int c = 0; c < CAT; ++c) {
        y0[c] = __expf(pW0[c] - mx0); s0 += y0[c];
        y1[c] = __expf(pW1[c] - mx1); s1 += y1[c];
    }
    const float i0 = 1.f / s0, i1 = 1.f / s1;
    float cls = 0.f, kl = 0.f;
    #pragma unroll
    for (int c = 0; c < CAT; ++c) {
        y0[c] *= i0; y1[c] *= i1;
        cls += y0[c] * (-pR0[c] * (1.f / IN)) + y1[c] * (-pR1[c] * (1.f / IN));
        const float yt0 = y_target[(size_t)r0 * CAT + c];
        const float yt1 = y_target[(size_t)(r0 + 1) * CAT + c];
        kl += y0[c] * (__logf(EPSF + y0[c]) - __logf(EPSF + yt0));
        kl += y1[c] * (__logf(EPSF + y1[c]) - __logf(EPSF + yt1));
    }

    // ---- write y rows (lane 0 -> r0, lane 1 -> r0+1), float2 stores
    float ys[CAT];
    #pragma unroll
    for (int c = 0; c < CAT; ++c) ys[c] = (l & 1) ? y1[c] : y0[c];
    if (l < 2) {
        float* op = out + (size_t)(r0 + l) * CAT;
        #pragma unroll
        for (int j = 0; j < 5; ++j) {
            float2 v = make_float2(ys[2 * j], ys[2 * j + 1]);
            *(float2*)(op + 2 * j) = v;
        }
    }

    // ---- per-block loss partial (reuse table LDS after barrier)
    __syncthreads();
    float2* pp = (float2*)lds;
    if (l == 0) pp[w] = make_float2(cls, kl);
    __syncthreads();
    if (tid == 0) {
        float c2 = 0.f, k2 = 0.f;
        #pragma unroll
        for (int w2 = 0; w2 < 8; ++w2) { c2 += pp[w2].x; k2 += pp[w2].y; }
        part[blockIdx.x] = make_float2(c2, k2);
    }
}

__global__ void final_kernel(const float2* __restrict__ part,
                             const double* __restrict__ acc,
                             float* __restrict__ out) {
    double c = 0.0, k = 0.0;
    for (int i = threadIdx.x; i < NBLK; i += 256) {
        float2 v = part[i];
        c += (double)v.x; k += (double)v.y;
    }
    #pragma unroll
    for (int o = 32; o; o >>= 1) {
        c += __shfl_down(c, o, 64);
        k += __shfl_down(k, o, 64);
    }
    __shared__ double rc[4], rk[4];
    if ((threadIdx.x & 63) == 0) { rc[threadIdx.x >> 6] = c; rk[threadIdx.x >> 6] = k; }
    __syncthreads();
    if (threadIdx.x == 0) {
        double C = rc[0] + rc[1] + rc[2] + rc[3];
        double K = rk[0] + rk[1] + rk[2] + rk[3];
        double loss = C / (double)B_SZ + 1e-4 * (K / (double)B_SZ)
                    + (0.005 / (double)SRCN / (double)CAT / (double)CAT) * acc[2];
        out[(size_t)B_SZ * CAT] = (float)loss;
    }
}

extern "C" void kernel_launch(void* const* d_in, const int* in_sizes, int n_in,
                              void* d_out, int out_size, void* d_ws, size_t ws_size,
                              hipStream_t stream) {
    const float* x        = (const float*)d_in[0];
    const float* mask     = (const float*)d_in[1];
    const float* y_target = (const float*)d_in[2];
    const float* W_rec    = (const float*)d_in[3];
    const float* b_rec    = (const float*)d_in[4];
    const float* W_yc     = (const float*)d_in[5];
    const float* b_yc     = (const float*)d_in[6];
    float* out  = (float*)d_out;
    double* acc = (double*)d_ws;
    short* logp_t = (short*)((char*)d_ws + 256);
    short* wyc_t  = logp_t + CAT * KPAD;
    float2* part  = (float2*)((char*)d_ws + 256 + 2 * TBYTES);

    // 80 table blocks (10*2048 entries) + 1 l1 block
    prep_kernel<<<81, 256, 0, stream>>>(W_rec, b_rec, W_yc, logp_t, wyc_t, acc);
    // 1024 blocks x 8 waves x 2 rows = 16384 rows
    main_kernel<<<NBLK, 512, 0, stream>>>(x, mask, y_target, b_yc,
                                          logp_t, wyc_t, out, part);
    final_kernel<<<1, 256, 0, stream>>>(part, acc, out);
}

// Round 6
// 230.322 us; speedup vs baseline: 1.4039x; 1.4039x over previous
//
#include <hip/hip_runtime.h>
#include <hip/hip_bf16.h>

#define B_SZ 16384
#define SRCN 200
#define CAT  10
#define IN   2000
#define KPAD 2048
#define TBYTES 40960       // one table: 10 * 2048 * 2B
#define NBLK 1024
#define EPSF 1e-10f

typedef short short8 __attribute__((ext_vector_type(8)));

// round-to-nearest-even f32 -> bf16 (bit trick)
__device__ __forceinline__ short f2bf(float f) {
    union { float f; unsigned u; } v; v.f = f;
    unsigned r = (v.u + 0x7fffu + ((v.u >> 16) & 1u)) >> 16;
    return (short)r;
}

__device__ __forceinline__ void bf2x2(unsigned u, float& a, float& b) {
    union { unsigned u; float f; } lo, hi;
    lo.u = u << 16; hi.u = u & 0xffff0000u;
    a = lo.f; b = hi.f;
}

// ---------------------------------------------------------------------------
// Prep: bf16 tables logp_t[10][2048], wyc_t[10][2048] (zero-padded cols),
// l1 = sum|W_yc| -> acc[2].
// ---------------------------------------------------------------------------
__global__ void prep_kernel(const float* __restrict__ W_rec,
                            const float* __restrict__ b_rec,
                            const float* __restrict__ W_yc,
                            short* __restrict__ logp_t,
                            short* __restrict__ wyc_t,
                            double* __restrict__ acc) {
    if (blockIdx.x == gridDim.x - 1) {
        float p = 0.f;
        for (int i = threadIdx.x; i < IN * CAT; i += blockDim.x) p += fabsf(W_yc[i]);
        __shared__ float red[4];
        for (int o = 32; o; o >>= 1) p += __shfl_down(p, o, 64);
        if ((threadIdx.x & 63) == 0) red[threadIdx.x >> 6] = p;
        __syncthreads();
        if (threadIdx.x == 0) acc[2] = (double)(red[0] + red[1] + red[2] + red[3]);
        return;
    }
    int tid = blockIdx.x * blockDim.x + threadIdx.x;   // 0 .. 20479
    int n = tid >> 11;          // 0..9
    int k = tid & 2047;
    short wv = 0, lv = 0;
    if (k < IN) {
        wv = f2bf(W_yc[k * CAT + n]);
        int base = (k / CAT) * CAT;
        float lg[CAT];
        float m = -1e30f;
        #pragma unroll
        for (int i = 0; i < CAT; i++) {
            lg[i] = W_rec[n * IN + base + i] + b_rec[base + i];
            m = fmaxf(m, lg[i]);
        }
        float s = 0.f;
        #pragma unroll
        for (int i = 0; i < CAT; i++) s += expf(lg[i] - m);
        float myl = W_rec[n * IN + k] + b_rec[k];
        float pp = expf(myl - m) / s;
        lv = f2bf(logf(EPSF + pp));
    }
    wyc_t[n * KPAD + k] = wv;
    logp_t[n * KPAD + k] = lv;
}

// ---------------------------------------------------------------------------
// Main: pure streaming VALU. Block = 512 threads (8 waves), 80 KB LDS tables
// (LDS-limited to 2 blocks/CU -> 16 waves/CU). Wave owns 2 rows; lane l
// streams cols {l*4 + 256*i} as float4 (contiguous 1KB per wave-load,
// register double-buffered). 40 f32 accumulators/lane, butterfly-reduced.
// launch_bounds min-occupancy arg = 2 so the VGPR cap is >=128 under either
// (waves/EU | blocks/CU) interpretation -- R5's cap of 64 caused ~800MB of
// scratch spill traffic per dispatch.
// ---------------------------------------------------------------------------
__global__ __launch_bounds__(512, 2) void main_kernel(
        const float* __restrict__ x, const float* __restrict__ mask,
        const float* __restrict__ y_target, const float* __restrict__ b_yc,
        const short* __restrict__ logp_t, const short* __restrict__ wyc_t,
        float* __restrict__ out, float2* __restrict__ part) {
    __shared__ __attribute__((aligned(16))) char lds[2 * TBYTES];   // 80 KB

    const int tid = threadIdx.x;
    {   // stage both tables: 2*2560 short8
        short8* d = (short8*)lds;
        const short8* s1 = (const short8*)logp_t;
        const short8* s2 = (const short8*)wyc_t;
        #pragma unroll
        for (int i = 0; i < 5; ++i) {
            d[i * 512 + tid]        = s1[i * 512 + tid];
            d[2560 + i * 512 + tid] = s2[i * 512 + tid];
        }
    }
    __syncthreads();

    const int l  = tid & 63;
    const int w  = tid >> 6;                // 0..7
    const int r0 = (blockIdx.x * 8 + w) * 2;

    const float* xr0 = x + (size_t)r0 * IN;
    const float* xr1 = xr0 + IN;
    const float* mr0 = mask + (size_t)r0 * IN;
    const float* mr1 = mr0 + IN;

    float pR0[CAT], pR1[CAT], pW0[CAT], pW1[CAT];
    #pragma unroll
    for (int c = 0; c < CAT; ++c) { pR0[c] = pR1[c] = pW0[c] = pW1[c] = 0.f; }

    const int c0 = l * 4;
    float4 cx0 = *(const float4*)(xr0 + c0);
    float4 cx1 = *(const float4*)(xr1 + c0);
    float4 cm0 = *(const float4*)(mr0 + c0);
    float4 cm1 = *(const float4*)(mr1 + c0);

    #pragma unroll
    for (int i = 0; i < 8; ++i) {
        // prefetch next strip (register double-buffer)
        float4 nx0 = {0,0,0,0}, nx1 = {0,0,0,0}, nm0 = {0,0,0,0}, nm1 = {0,0,0,0};
        if (i < 7) {
            const int nb = (i + 1) * 256 + l * 4;
            if ((i < 6) || (nb + 3 < IN)) {     // i<6 folds to unconditional
                nx0 = *(const float4*)(xr0 + nb);
                nx1 = *(const float4*)(xr1 + nb);
                nm0 = *(const float4*)(mr0 + nb);
                nm1 = *(const float4*)(mr1 + nb);
            }
        }
        const float X0[4] = {cx0.x, cx0.y, cx0.z, cx0.w};
        const float X1[4] = {cx1.x, cx1.y, cx1.z, cx1.w};
        const float XM0[4] = {cx0.x * cm0.x, cx0.y * cm0.y, cx0.z * cm0.z, cx0.w * cm0.w};
        const float XM1[4] = {cx1.x * cm1.x, cx1.y * cm1.y, cx1.z * cm1.z, cx1.w * cm1.w};

        const int off = i * 512 + l * 8;        // byte offset within a table row
        #pragma unroll
        for (int c = 0; c < CAT; ++c) {
            const uint2 ulp = *(const uint2*)(lds + c * 4096 + off);
            const uint2 uwy = *(const uint2*)(lds + TBYTES + c * 4096 + off);
            float l0, l1v, l2, l3, w0, w1, w2, w3;
            bf2x2(ulp.x, l0, l1v); bf2x2(ulp.y, l2, l3);
            bf2x2(uwy.x, w0, w1);  bf2x2(uwy.y, w2, w3);
            pR0[c] += XM0[0] * l0 + XM0[1] * l1v + XM0[2] * l2 + XM0[3] * l3;
            pR1[c] += XM1[0] * l0 + XM1[1] * l1v + XM1[2] * l2 + XM1[3] * l3;
            pW0[c] += X0[0] * w0 + X0[1] * w1 + X0[2] * w2 + X0[3] * w3;
            pW1[c] += X1[0] * w0 + X1[1] * w1 + X1[2] * w2 + X1[3] * w3;
        }
        cx0 = nx0; cx1 = nx1; cm0 = nm0; cm1 = nm1;
    }

    // ---- cross-lane reduce all 40 accumulators
    #pragma unroll
    for (int c = 0; c < CAT; ++c) {
        #pragma unroll
        for (int o = 1; o < 64; o <<= 1) {
            pR0[c] += __shfl_xor(pR0[c], o, 64);
            pR1[c] += __shfl_xor(pR1[c], o, 64);
            pW0[c] += __shfl_xor(pW0[c], o, 64);
            pW1[c] += __shfl_xor(pW1[c], o, 64);
        }
    }

    // ---- softmax + losses (computed redundantly on all lanes)
    float y0[CAT], y1[CAT];
    float mx0 = -1e30f, mx1 = -1e30f;
    #pragma unroll
    for (int c = 0; c < CAT; ++c) {
        const float by = b_yc[c];
        pW0[c] += by; pW1[c] += by;
        mx0 = fmaxf(mx0, pW0[c]); mx1 = fmaxf(mx1, pW1[c]);
    }
    float s0 = 0.f, s1 = 0.f;
    #pragma unroll
    for (int c = 0; c < CAT; ++c) {
        y0[c] = __expf(pW0[c] - mx0); s0 += y0[c];
        y1[c] = __expf(pW1[c] - mx1); s1 += y1[c];
    }
    const float i0 = 1.f / s0, i1 = 1.f / s1;
    float cls = 0.f, kl = 0.f;
    #pragma unroll
    for (int c = 0; c < CAT; ++c) {
        y0[c] *= i0; y1[c] *= i1;
        cls += y0[c] * (-pR0[c] * (1.f / IN)) + y1[c] * (-pR1[c] * (1.f / IN));
        const float yt0 = y_target[(size_t)r0 * CAT + c];
        const float yt1 = y_target[(size_t)(r0 + 1) * CAT + c];
        kl += y0[c] * (__logf(EPSF + y0[c]) - __logf(EPSF + yt0));
        kl += y1[c] * (__logf(EPSF + y1[c]) - __logf(EPSF + yt1));
    }

    // ---- write y rows (lane 0 -> r0, lane 1 -> r0+1), float2 stores
    float ys[CAT];
    #pragma unroll
    for (int c = 0; c < CAT; ++c) ys[c] = (l & 1) ? y1[c] : y0[c];
    if (l < 2) {
        float* op = out + (size_t)(r0 + l) * CAT;
        #pragma unroll
        for (int j = 0; j < 5; ++j) {
            float2 v = make_float2(ys[2 * j], ys[2 * j + 1]);
            *(float2*)(op + 2 * j) = v;
        }
    }

    // ---- per-block loss partial (reuse table LDS after barrier)
    __syncthreads();
    float2* pp = (float2*)lds;
    if (l == 0) pp[w] = make_float2(cls, kl);
    __syncthreads();
    if (tid == 0) {
        float c2 = 0.f, k2 = 0.f;
        #pragma unroll
        for (int w2 = 0; w2 < 8; ++w2) { c2 += pp[w2].x; k2 += pp[w2].y; }
        part[blockIdx.x] = make_float2(c2, k2);
    }
}

__global__ void final_kernel(const float2* __restrict__ part,
                             const double* __restrict__ acc,
                             float* __restrict__ out) {
    double c = 0.0, k = 0.0;
    for (int i = threadIdx.x; i < NBLK; i += 256) {
        float2 v = part[i];
        c += (double)v.x; k += (double)v.y;
    }
    #pragma unroll
    for (int o = 32; o; o >>= 1) {
        c += __shfl_down(c, o, 64);
        k += __shfl_down(k, o, 64);
    }
    __shared__ double rc[4], rk[4];
    if ((threadIdx.x & 63) == 0) { rc[threadIdx.x >> 6] = c; rk[threadIdx.x >> 6] = k; }
    __syncthreads();
    if (threadIdx.x == 0) {
        double C = rc[0] + rc[1] + rc[2] + rc[3];
        double K = rk[0] + rk[1] + rk[2] + rk[3];
        double loss = C / (double)B_SZ + 1e-4 * (K / (double)B_SZ)
                    + (0.005 / (double)SRCN / (double)CAT / (double)CAT) * acc[2];
        out[(size_t)B_SZ * CAT] = (float)loss;
    }
}

extern "C" void kernel_launch(void* const* d_in, const int* in_sizes, int n_in,
                              void* d_out, int out_size, void* d_ws, size_t ws_size,
                              hipStream_t stream) {
    const float* x        = (const float*)d_in[0];
    const float* mask     = (const float*)d_in[1];
    const float* y_target = (const float*)d_in[2];
    const float* W_rec    = (const float*)d_in[3];
    const float* b_rec    = (const float*)d_in[4];
    const float* W_yc     = (const float*)d_in[5];
    const float* b_yc     = (const float*)d_in[6];
    float* out  = (float*)d_out;
    double* acc = (double*)d_ws;
    short* logp_t = (short*)((char*)d_ws + 256);
    short* wyc_t  = logp_t + CAT * KPAD;
    float2* part  = (float2*)((char*)d_ws + 256 + 2 * TBYTES);

    // 80 table blocks (10*2048 entries) + 1 l1 block
    prep_kernel<<<81, 256, 0, stream>>>(W_rec, b_rec, W_yc, logp_t, wyc_t, acc);
    // 1024 blocks x 8 waves x 2 rows = 16384 rows
    main_kernel<<<NBLK, 512, 0, stream>>>(x, mask, y_target, b_yc,
                                          logp_t, wyc_t, out, part);
    final_kernel<<<1, 256, 0, stream>>>(part, acc, out);
}

// Round 8
// 79.794 us; speedup vs baseline: 4.0523x; 2.8865x over previous
//
#include <hip/hip_runtime.h>
#include <hip/hip_bf16.h>

#define B_SZ 16384
#define SRCN 200
#define CAT  10
#define IN   2000
#define QCOL 500           // f32 cols per K-quarter
#define QPAD 512           // padded quarter cols
#define NCHQ 8             // 8 chunks x 64 cols per quarter
#define TQB  10240         // one quarter-table: 10 * 512 * 2B
#define LDS_BUF0 20480     // buffers start after 2 tables
#define EPSF 1e-10f

typedef float f32x4 __attribute__((ext_vector_type(4)));
typedef _Float16 half2v __attribute__((ext_vector_type(2)));

#if __has_builtin(__builtin_amdgcn_fdot2)
__device__ __forceinline__ float fdot2(half2v a, half2v b, float c) {
    return __builtin_amdgcn_fdot2(a, b, c, false);
}
#else
__device__ __forceinline__ float fdot2(half2v a, half2v b, float c) {
    return c + (float)a[0] * (float)b[0] + (float)a[1] * (float)b[1];
}
#endif

__device__ __forceinline__ half2v pkrtz(float a, float b) {
#if __has_builtin(__builtin_amdgcn_cvt_pkrtz)
    union { __fp16 __attribute__((ext_vector_type(2))) i; half2v o; } v;
    v.i = __builtin_amdgcn_cvt_pkrtz(a, b);
    return v.o;
#else
    half2v r; r[0] = (_Float16)a; r[1] = (_Float16)b; return r;
#endif
}

__device__ __forceinline__ half2v as_h2(unsigned u) {
    union { unsigned u; half2v h; } v; v.u = u; return v.h;
}

__device__ __forceinline__ short f2h(float f) {
    union { _Float16 h; short s; } v; v.h = (_Float16)f; return v.s;
}

// async global->LDS, 16B/lane: dest = uniform base + lane*16; source per-lane.
__device__ __forceinline__ void gload16(const void* g, void* l) {
    __builtin_amdgcn_global_load_lds(
        (const __attribute__((address_space(1))) void*)g,
        (__attribute__((address_space(3))) void*)l,
        16, 0, 0);
}

// ---------------------------------------------------------------------------
// Prep: f16 quarter-tables lp4/wy4 [q][cat][512] (zero-padded past col 500),
// l1 = sum|W_yc| -> acc[2], zero acc[0..1].
// ---------------------------------------------------------------------------
__global__ void prep_kernel(const float* __restrict__ W_rec,
                            const float* __restrict__ b_rec,
                            const float* __restrict__ W_yc,
                            short* __restrict__ lp4,
                            short* __restrict__ wy4,
                            double* __restrict__ acc) {
    if (blockIdx.x == gridDim.x - 1) {
        float p = 0.f;
        for (int i = threadIdx.x; i < IN * CAT; i += blockDim.x) p += fabsf(W_yc[i]);
        __shared__ float red[4];
        for (int o = 32; o; o >>= 1) p += __shfl_down(p, o, 64);
        if ((threadIdx.x & 63) == 0) red[threadIdx.x >> 6] = p;
        __syncthreads();
        if (threadIdx.x == 0) {
            acc[0] = 0.0; acc[1] = 0.0;
            acc[2] = (double)(red[0] + red[1] + red[2] + red[3]);
        }
        return;
    }
    int idx = blockIdx.x * blockDim.x + threadIdx.x;   // 0 .. 20479
    int q   = idx / (CAT * QPAD);
    int rem = idx % (CAT * QPAD);
    int n   = rem >> 9;          // cat
    int kk  = rem & 511;
    short wv = 0, lv = 0;
    if (kk < QCOL) {
        int k = q * QCOL + kk;                 // global col, < 2000
        wv = f2h(W_yc[k * CAT + n]);
        int base = (k / CAT) * CAT;
        float lg[CAT];
        float m = -1e30f;
        #pragma unroll
        for (int i = 0; i < CAT; i++) {
            lg[i] = W_rec[n * IN + base + i] + b_rec[base + i];
            m = fmaxf(m, lg[i]);
        }
        float s = 0.f;
        #pragma unroll
        for (int i = 0; i < CAT; i++) s += expf(lg[i] - m);
        float myl = W_rec[n * IN + k] + b_rec[k];
        float pp = expf(myl - m) / s;
        lv = f2h(logf(EPSF + pp));
    }
    lp4[idx] = lv;
    wy4[idx] = wv;
}

// ---------------------------------------------------------------------------
// Main: block = 32 rows x one K-quarter; 8 waves, wave owns 4 rows.
// x/mask stream via global_load_lds DMA into per-wave double-buffered 2KB
// slots (counted vmcnt(2), NO barriers in the loop -- each wave waits only on
// its own DMA). Tables f16 in LDS (lgkmcnt domain, vmcnt stays pure).
// Lane: g=l>>4 picks the row, li=l&15 picks 4 cols; dot2 accumulate, 4-step
// butterfly within 16-lane groups, partials -> ws.
// ---------------------------------------------------------------------------
__global__ __launch_bounds__(512, 3) void main_kernel(
        const float* __restrict__ x, const float* __restrict__ mask,
        const short* __restrict__ lp4, const short* __restrict__ wy4,
        float* __restrict__ part) {
    __shared__ __attribute__((aligned(16))) char lds[LDS_BUF0 + 8 * 4096]; // 52KB

    const int tid = threadIdx.x;
    {   // stage this quarter's tables: 2 x 640 uint4
        const int q = blockIdx.x & 3;
        const uint4* s1 = (const uint4*)(lp4 + q * (CAT * QPAD));
        const uint4* s2 = (const uint4*)(wy4 + q * (CAT * QPAD));
        uint4* d1 = (uint4*)lds;
        uint4* d2 = (uint4*)(lds + TQB);
        #pragma unroll
        for (int i = 0; i < 2; ++i) {
            int j = i * 512 + tid;
            if (j < 640) { d1[j] = s1[j]; d2[j] = s2[j]; }
        }
    }
    __syncthreads();

    const int l  = tid & 63;
    const int w  = tid >> 6;                 // 0..7
    const int g  = l >> 4;                   // row-in-wave 0..3
    const int li = l & 15;                   // col group
    const int rt = blockIdx.x >> 2;
    const int q  = blockIdx.x & 3;
    const int row = rt * 32 + w * 4 + g;

    const float* xrow = x + (size_t)row * IN;
    const float* mrow = mask + (size_t)row * IN;
    const int colb = q * QCOL + li * 4;
    char* buf = lds + LDS_BUF0 + w * 4096;

    float pR[CAT], pW[CAT];
    #pragma unroll
    for (int c = 0; c < CAT; ++c) { pR[c] = 0.f; pW[c] = 0.f; }

    auto stage = [&](int cc) {
        int col = colb + cc * 64;
        if (col > IN - 4) col = IN - 4;      // tail clamp; table pad is 0
        char* slot = buf + (cc & 1) * 2048;
        gload16(xrow + col, slot);           // lanes: g*256 + li*16 -> [g][li]
        gload16(mrow + col, slot + 1024);
    };

    auto compute = [&](int cc) {
        char* slot = buf + (cc & 1) * 2048;
        const int myo = g * 256 + li * 16;
        f32x4 xv = *(const f32x4*)(slot + myo);
        f32x4 mv = *(const f32x4*)(slot + 1024 + myo);
        half2v ax0 = pkrtz(xv[0], xv[1]);
        half2v ax1 = pkrtz(xv[2], xv[3]);
        half2v am0 = pkrtz(xv[0] * mv[0], xv[1] * mv[1]);
        half2v am1 = pkrtz(xv[2] * mv[2], xv[3] * mv[3]);
        const int tb = cc * 128 + li * 8;    // byte offset in [512]-col cat row
        #pragma unroll
        for (int c = 0; c < CAT; ++c) {
            const uint2 lpv = *(const uint2*)(lds + c * 1024 + tb);
            const uint2 wyv = *(const uint2*)(lds + TQB + c * 1024 + tb);
            pR[c] = fdot2(am0, as_h2(lpv.x), pR[c]);
            pR[c] = fdot2(am1, as_h2(lpv.y), pR[c]);
            pW[c] = fdot2(ax0, as_h2(wyv.x), pW[c]);
            pW[c] = fdot2(ax1, as_h2(wyv.y), pW[c]);
        }
    };

    stage(0);
    stage(1);
    #pragma unroll
    for (int cc = 0; cc < NCHQ; ++cc) {
        if (cc < NCHQ - 1) { asm volatile("s_waitcnt vmcnt(2)" ::: "memory"); }
        else               { asm volatile("s_waitcnt vmcnt(0)" ::: "memory"); }
        compute(cc);
        asm volatile("s_waitcnt lgkmcnt(0)" ::: "memory");   // slot reads done
        if (cc + 2 < NCHQ) stage(cc + 2);
    }

    // ---- 4-step butterfly within each 16-lane group (one row per group)
    #pragma unroll
    for (int c = 0; c < CAT; ++c) {
        #pragma unroll
        for (int o = 1; o < 16; o <<= 1) {
            pR[c] += __shfl_xor(pR[c], o, 64);
            pW[c] += __shfl_xor(pW[c], o, 64);
        }
    }
    if (li == 0) {
        float* pp = part + ((size_t)row * 4 + q) * 20;
        #pragma unroll
        for (int c = 0; c < CAT; ++c) { pp[c] = pR[c]; pp[10 + c] = pW[c]; }
    }
}

// ---------------------------------------------------------------------------
// Combine: per row, sum 4 quarter-partials, softmax, write y, loss partials.
// ---------------------------------------------------------------------------
__global__ void combine_kernel(const float* __restrict__ part,
                               const float* __restrict__ y_target,
                               const float* __restrict__ b_yc,
                               float* __restrict__ out,
                               double* __restrict__ acc) {
    const int row = blockIdx.x * 256 + threadIdx.x;
    const float* pp = part + (size_t)row * 80;
    float pR[CAT], pW[CAT];
    #pragma unroll
    for (int c = 0; c < CAT; ++c) {
        pR[c] = pp[c] + pp[20 + c] + pp[40 + c] + pp[60 + c];
        pW[c] = pp[10 + c] + pp[30 + c] + pp[50 + c] + pp[70 + c] + b_yc[c];
    }
    float mx = -1e30f;
    #pragma unroll
    for (int c = 0; c < CAT; ++c) mx = fmaxf(mx, pW[c]);
    float y[CAT], s = 0.f;
    #pragma unroll
    for (int c = 0; c < CAT; ++c) { y[c] = __expf(pW[c] - mx); s += y[c]; }
    const float is = 1.f / s;
    float cls = 0.f, kl = 0.f;
    float* op = out + (size_t)row * CAT;
    #pragma unroll
    for (int c = 0; c < CAT; ++c) {
        y[c] *= is;
        op[c] = y[c];
        cls += y[c] * (-pR[c] * (1.f / IN));
        const float yt = y_target[(size_t)row * CAT + c];
        kl += y[c] * (__logf(EPSF + y[c]) - __logf(EPSF + yt));
    }
    // block reduction -> f64 atomics
    #pragma unroll
    for (int o = 32; o; o >>= 1) {
        cls += __shfl_down(cls, o, 64);
        kl  += __shfl_down(kl, o, 64);
    }
    __shared__ float rc[4], rk[4];
    if ((threadIdx.x & 63) == 0) {
        rc[threadIdx.x >> 6] = cls; rk[threadIdx.x >> 6] = kl;
    }
    __syncthreads();
    if (threadIdx.x == 0) {
        atomicAdd(&acc[0], (double)(rc[0] + rc[1] + rc[2] + rc[3]));
        atomicAdd(&acc[1], (double)(rk[0] + rk[1] + rk[2] + rk[3]));
    }
}

__global__ void final_kernel(const double* __restrict__ acc,
                             float* __restrict__ out) {
    if (threadIdx.x == 0) {
        double loss = acc[0] / (double)B_SZ
                    + 1e-4 * (acc[1] / (double)B_SZ)
                    + (0.005 / (double)SRCN / (double)CAT / (double)CAT) * acc[2];
        out[(size_t)B_SZ * CAT] = (float)loss;
    }
}

extern "C" void kernel_launch(void* const* d_in, const int* in_sizes, int n_in,
                              void* d_out, int out_size, void* d_ws, size_t ws_size,
                              hipStream_t stream) {
    const float* x        = (const float*)d_in[0];
    const float* mask     = (const float*)d_in[1];
    const float* y_target = (const float*)d_in[2];
    const float* W_rec    = (const float*)d_in[3];
    const float* b_rec    = (const float*)d_in[4];
    const float* W_yc     = (const float*)d_in[5];
    const float* b_yc     = (const float*)d_in[6];
    float* out  = (float*)d_out;
    double* acc = (double*)d_ws;
    short* lp4  = (short*)((char*)d_ws + 256);            // 4*10*512 f16 = 40960B
    short* wy4  = lp4 + 4 * CAT * QPAD;
    float* part = (float*)((char*)d_ws + 256 + 2 * 40960); // 16384*80 f32 = 5.24MB

    // 80 table blocks (20480 entries) + 1 l1/zero block
    prep_kernel<<<81, 256, 0, stream>>>(W_rec, b_rec, W_yc, lp4, wy4, acc);
    // 512 row-tiles of 32 rows x 4 K-quarters = 2048 blocks
    main_kernel<<<2048, 512, 0, stream>>>(x, mask, lp4, wy4, part);
    combine_kernel<<<64, 256, 0, stream>>>(part, y_target, b_yc, out, acc);
    final_kernel<<<1, 64, 0, stream>>>(acc, out);
}

// Round 9
// 72.990 us; speedup vs baseline: 4.4300x; 1.0932x over previous
//
#include <hip/hip_runtime.h>
#include <hip/hip_bf16.h>

#define B_SZ 16384
#define SRCN 200
#define CAT  10
#define IN   2000
#define QCOL 500           // f32 cols per K-quarter
#define QPAD 512           // padded quarter cols
#define TQB  10240         // one quarter-table: 10 * 512 * 2B
#define EPSF 1e-10f

typedef _Float16 half2v __attribute__((ext_vector_type(2)));

#if __has_builtin(__builtin_amdgcn_fdot2)
__device__ __forceinline__ float fdot2(half2v a, half2v b, float c) {
    return __builtin_amdgcn_fdot2(a, b, c, false);
}
#else
__device__ __forceinline__ float fdot2(half2v a, half2v b, float c) {
    return c + (float)a[0] * (float)b[0] + (float)a[1] * (float)b[1];
}
#endif

__device__ __forceinline__ half2v pkrtz(float a, float b) {
#if __has_builtin(__builtin_amdgcn_cvt_pkrtz)
    union { __fp16 __attribute__((ext_vector_type(2))) i; half2v o; } v;
    v.i = __builtin_amdgcn_cvt_pkrtz(a, b);
    return v.o;
#else
    half2v r; r[0] = (_Float16)a; r[1] = (_Float16)b; return r;
#endif
}

__device__ __forceinline__ half2v as_h2(unsigned u) {
    union { unsigned u; half2v h; } v; v.u = u; return v.h;
}

__device__ __forceinline__ short f2h(float f) {
    union { _Float16 h; short s; } v; v.h = (_Float16)f; return v.s;
}

// ---------------------------------------------------------------------------
// Prep: f16 quarter-tables lp4/wy4 [q][cat][512] (zero past col 500),
// l1 = sum|W_yc| -> acc[2], zero acc[0..1].
// ---------------------------------------------------------------------------
__global__ void prep_kernel(const float* __restrict__ W_rec,
                            const float* __restrict__ b_rec,
                            const float* __restrict__ W_yc,
                            short* __restrict__ lp4,
                            short* __restrict__ wy4,
                            double* __restrict__ acc) {
    if (blockIdx.x == gridDim.x - 1) {
        float p = 0.f;
        for (int i = threadIdx.x; i < IN * CAT; i += blockDim.x) p += fabsf(W_yc[i]);
        __shared__ float red[4];
        for (int o = 32; o; o >>= 1) p += __shfl_down(p, o, 64);
        if ((threadIdx.x & 63) == 0) red[threadIdx.x >> 6] = p;
        __syncthreads();
        if (threadIdx.x == 0) {
            acc[0] = 0.0; acc[1] = 0.0;
            acc[2] = (double)(red[0] + red[1] + red[2] + red[3]);
        }
        return;
    }
    int idx = blockIdx.x * blockDim.x + threadIdx.x;   // 0 .. 20479
    int q   = idx / (CAT * QPAD);
    int rem = idx % (CAT * QPAD);
    int n   = rem >> 9;          // cat
    int kk  = rem & 511;
    short wv = 0, lv = 0;
    if (kk < QCOL) {
        int k = q * QCOL + kk;                 // global col, < 2000
        wv = f2h(W_yc[k * CAT + n]);
        int base = (k / CAT) * CAT;
        float lg[CAT];
        float m = -1e30f;
        #pragma unroll
        for (int i = 0; i < CAT; i++) {
            lg[i] = W_rec[n * IN + base + i] + b_rec[base + i];
            m = fmaxf(m, lg[i]);
        }
        float s = 0.f;
        #pragma unroll
        for (int i = 0; i < CAT; i++) s += expf(lg[i] - m);
        float myl = W_rec[n * IN + k] + b_rec[k];
        float pp = expf(myl - m) / s;
        lv = f2h(logf(EPSF + pp));
    }
    lp4[idx] = lv;
    wy4[idx] = wv;
}

// ---------------------------------------------------------------------------
// Main: block = 16 rows x one K-quarter; 4 waves, wave owns 4 rows
// (g = l>>4 picks the row, li = l&15 picks 4 cols). ALL 16 chunk loads
// (8 x-float4 + 8 m-float4 per lane, 16 KB per wave) are issued up front
// into named registers (one base pointer + imm offsets) -> max in-flight,
// counted waits by the compiler, no barriers, no LDS round-trip for x/mask.
// Tables f16 in 20 KB LDS. dot2 accumulate; 4-step butterfly per 16-lane
// group; per-(row,quarter) partials -> ws.
// ---------------------------------------------------------------------------
__global__ __launch_bounds__(256, 4) void main_kernel(
        const float* __restrict__ x, const float* __restrict__ mask,
        const short* __restrict__ lp4, const short* __restrict__ wy4,
        float* __restrict__ part) {
    __shared__ __attribute__((aligned(16))) char lds[2 * TQB];   // 20 KB

    const int q = blockIdx.x & 3;
    {   // stage this quarter's tables: 2 x 640 uint4
        const uint4* s1 = (const uint4*)(lp4 + q * (CAT * QPAD));
        const uint4* s2 = (const uint4*)(wy4 + q * (CAT * QPAD));
        uint4* d1 = (uint4*)lds;
        uint4* d2 = (uint4*)(lds + TQB);
        #pragma unroll
        for (int i = 0; i < 3; ++i) {
            int j = i * 256 + threadIdx.x;
            if (j < 640) { d1[j] = s1[j]; d2[j] = s2[j]; }
        }
    }
    __syncthreads();

    const int l  = threadIdx.x & 63;
    const int w  = threadIdx.x >> 6;         // 0..3
    const int g  = l >> 4;                   // row-in-wave
    const int li = l & 15;                   // col group
    const int row = (blockIdx.x >> 2) * 16 + w * 4 + g;

    const int col0 = q * QCOL + li * 4;
    const float* xr = x + (size_t)row * IN + col0;
    const float* mr = mask + (size_t)row * IN + col0;

    // ---- issue ALL loads up front (chunk stride 64 f32 = 256 B imm offsets)
    float4 xv[8], mv[8];
    #pragma unroll
    for (int cc = 0; cc < 7; ++cc) {
        xv[cc] = *(const float4*)(xr + cc * 64);
        mv[cc] = *(const float4*)(mr + cc * 64);
    }
    {   // chunk 7: clamp (only q=3, li>=13 overruns; table cols >=500 are 0)
        const int base = col0 + 7 * 64;
        const int adj = (base > IN - 4) ? (base - (IN - 4)) : 0;
        xv[7] = *(const float4*)(xr + 7 * 64 - adj);
        mv[7] = *(const float4*)(mr + 7 * 64 - adj);
    }

    float pR[CAT], pW[CAT];
    #pragma unroll
    for (int c = 0; c < CAT; ++c) { pR[c] = 0.f; pW[c] = 0.f; }

    #pragma unroll
    for (int cc = 0; cc < 8; ++cc) {
        const half2v ax0 = pkrtz(xv[cc].x, xv[cc].y);
        const half2v ax1 = pkrtz(xv[cc].z, xv[cc].w);
        const half2v am0 = pkrtz(xv[cc].x * mv[cc].x, xv[cc].y * mv[cc].y);
        const half2v am1 = pkrtz(xv[cc].z * mv[cc].z, xv[cc].w * mv[cc].w);
        const int tb = cc * 128 + li * 8;    // byte offset in [512]-col cat row
        #pragma unroll
        for (int c = 0; c < CAT; ++c) {
            const uint2 lpv = *(const uint2*)(lds + c * 1024 + tb);
            const uint2 wyv = *(const uint2*)(lds + TQB + c * 1024 + tb);
            pR[c] = fdot2(am0, as_h2(lpv.x), pR[c]);
            pR[c] = fdot2(am1, as_h2(lpv.y), pR[c]);
            pW[c] = fdot2(ax0, as_h2(wyv.x), pW[c]);
            pW[c] = fdot2(ax1, as_h2(wyv.y), pW[c]);
        }
    }

    // ---- 4-step butterfly within each 16-lane group (one row per group)
    #pragma unroll
    for (int c = 0; c < CAT; ++c) {
        #pragma unroll
        for (int o = 1; o < 16; o <<= 1) {
            pR[c] += __shfl_xor(pR[c], o, 64);
            pW[c] += __shfl_xor(pW[c], o, 64);
        }
    }
    if (li == 0) {
        float* pp = part + ((size_t)row * 4 + q) * 20;
        #pragma unroll
        for (int c = 0; c < CAT; ++c) { pp[c] = pR[c]; pp[10 + c] = pW[c]; }
    }
}

// ---------------------------------------------------------------------------
// Combine: per row, sum 4 quarter-partials, softmax, write y, loss partials.
// ---------------------------------------------------------------------------
__global__ void combine_kernel(const float* __restrict__ part,
                               const float* __restrict__ y_target,
                               const float* __restrict__ b_yc,
                               float* __restrict__ out,
                               double* __restrict__ acc) {
    const int row = blockIdx.x * 256 + threadIdx.x;
    const float* pp = part + (size_t)row * 80;
    float pR[CAT], pW[CAT];
    #pragma unroll
    for (int c = 0; c < CAT; ++c) {
        pR[c] = pp[c] + pp[20 + c] + pp[40 + c] + pp[60 + c];
        pW[c] = pp[10 + c] + pp[30 + c] + pp[50 + c] + pp[70 + c] + b_yc[c];
    }
    float mx = -1e30f;
    #pragma unroll
    for (int c = 0; c < CAT; ++c) mx = fmaxf(mx, pW[c]);
    float y[CAT], s = 0.f;
    #pragma unroll
    for (int c = 0; c < CAT; ++c) { y[c] = __expf(pW[c] - mx); s += y[c]; }
    const float is = 1.f / s;
    float cls = 0.f, kl = 0.f;
    float* op = out + (size_t)row * CAT;
    #pragma unroll
    for (int c = 0; c < CAT; ++c) {
        y[c] *= is;
        op[c] = y[c];
        cls += y[c] * (-pR[c] * (1.f / IN));
        const float yt = y_target[(size_t)row * CAT + c];
        kl += y[c] * (__logf(EPSF + y[c]) - __logf(EPSF + yt));
    }
    // block reduction -> f64 atomics
    #pragma unroll
    for (int o = 32; o; o >>= 1) {
        cls += __shfl_down(cls, o, 64);
        kl  += __shfl_down(kl, o, 64);
    }
    __shared__ float rc[4], rk[4];
    if ((threadIdx.x & 63) == 0) {
        rc[threadIdx.x >> 6] = cls; rk[threadIdx.x >> 6] = kl;
    }
    __syncthreads();
    if (threadIdx.x == 0) {
        atomicAdd(&acc[0], (double)(rc[0] + rc[1] + rc[2] + rc[3]));
        atomicAdd(&acc[1], (double)(rk[0] + rk[1] + rk[2] + rk[3]));
    }
}

__global__ void final_kernel(const double* __restrict__ acc,
                             float* __restrict__ out) {
    if (threadIdx.x == 0) {
        double loss = acc[0] / (double)B_SZ
                    + 1e-4 * (acc[1] / (double)B_SZ)
                    + (0.005 / (double)SRCN / (double)CAT / (double)CAT) * acc[2];
        out[(size_t)B_SZ * CAT] = (float)loss;
    }
}

extern "C" void kernel_launch(void* const* d_in, const int* in_sizes, int n_in,
                              void* d_out, int out_size, void* d_ws, size_t ws_size,
                              hipStream_t stream) {
    const float* x        = (const float*)d_in[0];
    const float* mask     = (const float*)d_in[1];
    const float* y_target = (const float*)d_in[2];
    const float* W_rec    = (const float*)d_in[3];
    const float* b_rec    = (const float*)d_in[4];
    const float* W_yc     = (const float*)d_in[5];
    const float* b_yc     = (const float*)d_in[6];
    float* out  = (float*)d_out;
    double* acc = (double*)d_ws;
    short* lp4  = (short*)((char*)d_ws + 256);            // 4*10*512 f16
    short* wy4  = lp4 + 4 * CAT * QPAD;
    float* part = (float*)((char*)d_ws + 256 + 2 * 40960); // 16384*80 f32

    // 80 table blocks (20480 entries) + 1 l1/zero block
    prep_kernel<<<81, 256, 0, stream>>>(W_rec, b_rec, W_yc, lp4, wy4, acc);
    // 1024 row-tiles of 16 rows x 4 K-quarters = 4096 blocks
    main_kernel<<<4096, 256, 0, stream>>>(x, mask, lp4, wy4, part);
    combine_kernel<<<64, 256, 0, stream>>>(part, y_target, b_yc, out, acc);
    final_kernel<<<1, 64, 0, stream>>>(acc, out);
}